// Round 1
// baseline (1969.080 us; speedup 1.0000x reference)
//
#include <hip/hip_runtime.h>
#include <hip/hip_bf16.h>
#include <stdint.h>

#define B_ 64
#define T_ 50
#define N_ 24
#define F_ 256
#define H_ 256
#define LDA 512
#define UTROW 24

typedef float f32x4 __attribute__((ext_vector_type(4)));
typedef short s16x8 __attribute__((ext_vector_type(8)));

// workspace byte offsets
#define WS_WCAT   0u          // [1024][512] bf16 : [W_ih | W_hh] rows=out col
#define WS_WINIT  1048576u    // [512][256] bf16  : rows 0-255 W_h1, 256-511 W_h2
#define WS_WFC    1310720u    // [256][256] bf16
#define WS_GPAD   1441792u    // [32][32] bf16 G[n][m] zero-padded
#define WS_BCAT   1443840u    // [1024] f32 (b_ih + b_hh)
#define WS_BINIT  1447936u    // [512] f32 (b_h1 | b_h2)
#define WS_BFC    1449984u    // [256] f32
#define WS_NEED   1451008u

__device__ __forceinline__ uint32_t bfbits(float f){
  uint32_t u = __builtin_bit_cast(uint32_t, f);
  u += 0x7FFFu + ((u >> 16) & 1u);   // RNE
  return u >> 16;
}
__device__ __forceinline__ uint32_t pk2bf(float lo, float hi){
  return bfbits(lo) | (bfbits(hi) << 16);
}
__device__ __forceinline__ f32x4 mfma16(s16x8 a, s16x8 b, f32x4 c){
  return __builtin_amdgcn_mfma_f32_16x16x32_bf16(a, b, c, 0, 0, 0);
}
__device__ __forceinline__ float fexp2(float x){ return __builtin_amdgcn_exp2f(x); }
__device__ __forceinline__ float frcp_(float x){ return __builtin_amdgcn_rcpf(x); }
#define LOG2E 1.4426950408889634f
__device__ __forceinline__ float fsig(float x){ return frcp_(1.f + fexp2(-LOG2E * x)); }
__device__ __forceinline__ float ftanh_(float x){ return 1.f - 2.f * frcp_(1.f + fexp2(2.f * LOG2E * x)); }

// ---------------- prep: convert weights to bf16 layouts ----------------
__global__ void prep_kernel(
    const float* __restrict__ G,
    const float* __restrict__ Wih, const float* __restrict__ bih,
    const float* __restrict__ Whh, const float* __restrict__ bhh,
    const float* __restrict__ Wh1, const float* __restrict__ bh1,
    const float* __restrict__ Wh2, const float* __restrict__ bh2,
    const float* __restrict__ Wfc, const float* __restrict__ bfc,
    uint8_t* __restrict__ ws)
{
  const int tid = blockIdx.x * blockDim.x + threadIdx.x;
  const int nth = gridDim.x * blockDim.x;
  uint16_t* wcat  = (uint16_t*)(ws + WS_WCAT);
  uint16_t* winit = (uint16_t*)(ws + WS_WINIT);
  uint16_t* wfcd  = (uint16_t*)(ws + WS_WFC);
  uint16_t* gpad  = (uint16_t*)(ws + WS_GPAD);
  float* bcat  = (float*)(ws + WS_BCAT);
  float* binit = (float*)(ws + WS_BINIT);
  float* bfcd  = (float*)(ws + WS_BFC);

  for (int i = tid; i < 1024*512; i += nth){
    int n = i >> 9, k = i & 511;
    float v = (k < 256) ? Wih[n*256 + k] : Whh[n*256 + k - 256];
    wcat[i] = (uint16_t)bfbits(v);
  }
  for (int i = tid; i < 512*256; i += nth){
    int n = i >> 8, k = i & 255;
    float v = (n < 256) ? Wh1[n*256 + k] : Wh2[(n-256)*256 + k];
    winit[i] = (uint16_t)bfbits(v);
  }
  for (int i = tid; i < 256*256; i += nth)
    wfcd[i] = (uint16_t)bfbits(Wfc[i]);
  for (int i = tid; i < 1024; i += nth){
    int n = i >> 5, m = i & 31;
    gpad[i] = (n < 24 && m < 24) ? (uint16_t)bfbits(G[n*24 + m]) : (uint16_t)0;
  }
  for (int i = tid; i < 1024; i += nth) bcat[i] = bih[i] + bhh[i];
  for (int i = tid; i < 512;  i += nth) binit[i] = (i < 256) ? bh1[i] : bh2[i - 256];
  for (int i = tid; i < 256;  i += nth) bfcd[i] = bfc[i];
}

// ---------------- GEMM helpers ----------------
// A in LDS: [25][512] bf16, row r swizzled: elem k stored at k ^ ((r&7)<<3); row 24 = zeros.
// u^T in LDS: [512][24] bf16 (+8 elem zero tail), row = u column (local within half).

template<int NKS, int KROW>
__device__ __forceinline__ void gemm_half(
    f32x4 (&acc)[4][2],
    const uint16_t* __restrict__ A_,
    const uint16_t* __restrict__ Wt,
    int aksbase,
    const int (&ct)[4], int l15, int g)
{
  const int r0  = l15;
  const int r1  = 16 + l15;
  const int r1e = (r1 < 24) ? r1 : 24;
  const uint16_t* arow0 = A_ + r0  * LDA;
  const uint16_t* arow1 = A_ + r1e * LDA;
  const int sw0 = (r0  & 7) << 3;
  const int sw1 = (r1e & 7) << 3;
  int brow[4];
  #pragma unroll
  for (int j = 0; j < 4; j++) brow[j] = (ct[j]*16 + l15) * KROW + g*8;

  #pragma unroll
  for (int i = 0; i < NKS; i++){
    const int ka = (aksbase + i)*32 + g*8;
    s16x8 a0 = *(const s16x8*)&arow0[ka ^ sw0];
    s16x8 a1 = *(const s16x8*)&arow1[ka ^ sw1];
    #pragma unroll
    for (int j = 0; j < 4; j++){
      s16x8 bb = *(const s16x8*)&Wt[brow[j] + i*32];
      acc[j][0] = mfma16(a0, bb, acc[j][0]);
      acc[j][1] = mfma16(a1, bb, acc[j][1]);
    }
  }
}

__device__ __forceinline__ void ut_write(
    uint16_t* utp, const f32x4 (&acc)[4][2],
    const int (&ct)[4], int l15, int g)
{
  #pragma unroll
  for (int j = 0; j < 4; j++){
    int cl = ((ct[j] & 31)*16 + l15) * UTROW;
    uint2 p0; p0.x = pk2bf(acc[j][0][0], acc[j][0][1]);
              p0.y = pk2bf(acc[j][0][2], acc[j][0][3]);
    *(uint2*)&utp[cl + g*4] = p0;
    if (g < 2){
      uint2 p1; p1.x = pk2bf(acc[j][1][0], acc[j][1][1]);
                p1.y = pk2bf(acc[j][1][2], acc[j][1][3]);
      *(uint2*)&utp[cl + 16 + g*4] = p1;
    }
  }
}

__device__ __forceinline__ void nodemix(
    f32x4 (&v)[4][2], const uint16_t* utp,
    const int (&ct)[4], int l15, int g,
    s16x8 gb0, s16x8 gb1)
{
  #pragma unroll
  for (int j = 0; j < 4; j++){
    s16x8 a = *(const s16x8*)&utp[((ct[j] & 31)*16 + l15) * UTROW + g*8];
    f32x4 z = {0.f, 0.f, 0.f, 0.f};
    v[j][0] = mfma16(a, gb0, z);
    v[j][1] = mfma16(a, gb1, z);
  }
}

// ---------------- main: one workgroup per batch ----------------
__global__ __launch_bounds__(512, 1)
void encoder_kernel(const float* __restrict__ x, const uint8_t* __restrict__ ws,
                    float* __restrict__ out)
{
  __shared__ uint16_t Alds[25 * LDA];          // [x_t | h] bf16, swizzled, row 24 = zero
  __shared__ uint16_t uTl[512 * UTROW + 8];    // u^T per half

  const int b   = blockIdx.x;
  const int tid = threadIdx.x;
  const int w   = tid >> 6;   // wave 0..7
  const int l   = tid & 63;
  const int l15 = l & 15;
  const int g   = l >> 4;

  const uint16_t* wcat  = (const uint16_t*)(ws + WS_WCAT);
  const uint16_t* winit = (const uint16_t*)(ws + WS_WINIT);
  const uint16_t* wfc   = (const uint16_t*)(ws + WS_WFC);
  const uint16_t* gpad  = (const uint16_t*)(ws + WS_GPAD);
  const float*    bcat  = (const float*)(ws + WS_BCAT);
  const float*    binit = (const float*)(ws + WS_BINIT);
  const float*    bfcp  = (const float*)(ws + WS_BFC);

  // zero the pad row and u^T tail
  for (int i = tid; i < LDA; i += 512) Alds[24*LDA + i] = 0;
  if (tid < 8) uTl[512*UTROW + tid] = 0;

  // G B-fragments (constant across steps): lane = col n, k = node m
  s16x8 gb0 = *(const s16x8*)&gpad[(l15     )*32 + g*8];
  s16x8 gb1 = *(const s16x8*)&gpad[(l15 + 16)*32 + g*8];

  // gate biases (col = (8p+w)*16 + g*4 + r)
  float bi[2][4], bff[2][4], bg[2][4], bo[2][4];
  #pragma unroll
  for (int p = 0; p < 2; p++)
    #pragma unroll
    for (int r = 0; r < 4; r++){
      int c = (8*p + w)*16 + g*4 + r;
      bi [p][r] = bcat[c];
      bff[p][r] = bcat[256 + c];
      bg [p][r] = bcat[512 + c];
      bo [p][r] = bcat[768 + c];
    }

  const int ctA[4] = {w, 8+w, 16+w, 24+w};
  const int ctB[4] = {32+w, 40+w, 48+w, 56+w};

  // load x0 into A (k < 256)
  {
    const float* xp = x + (size_t)b * T_ * N_ * F_;
    int f0 = (tid & 63)*4;
    #pragma unroll
    for (int p = 0; p < 3; p++){
      int n = p*8 + w;
      f32x4 v = *(const f32x4*)(xp + n*F_ + f0);
      uint2 pk; pk.x = pk2bf(v[0], v[1]); pk.y = pk2bf(v[2], v[3]);
      *(uint2*)&Alds[n*LDA + (f0 ^ ((n&7)<<3))] = pk;
    }
  }
  __syncthreads();

  float c_state[2][2][4];

  // ---- init: h0 = G(x0 Wh1^T)+bh1 ; c0 = G(x0 Wh2^T)+bh2
  {
    f32x4 acc[4][2] = {};
    gemm_half<8,256>(acc, Alds, winit, 0, ctA, l15, g);
    ut_write(uTl, acc, ctA, l15, g);
    __syncthreads();
    f32x4 v[4][2];
    nodemix(v, uTl, ctA, l15, g, gb0, gb1);
    #pragma unroll
    for (int p = 0; p < 2; p++){
      float bh1v[4], bh2v[4];
      #pragma unroll
      for (int r = 0; r < 4; r++){
        int c = (8*p + w)*16 + g*4 + r;
        bh1v[r] = binit[c];
        bh2v[r] = binit[256 + c];
      }
      #pragma unroll
      for (int nt = 0; nt < 2; nt++){
        #pragma unroll
        for (int r = 0; r < 4; r++)
          c_state[p][nt][r] = v[2+p][nt][r] + bh2v[r];
        int n = l15 + 16*nt;
        if (n < 24){
          float h0[4];
          #pragma unroll
          for (int r = 0; r < 4; r++) h0[r] = v[p][nt][r] + bh1v[r];
          uint2 pk; pk.x = pk2bf(h0[0], h0[1]); pk.y = pk2bf(h0[2], h0[3]);
          int c0 = (8*p + w)*16 + g*4;
          *(uint2*)&Alds[n*LDA + ((256 + c0) ^ ((n&7)<<3))] = pk;
        }
      }
    }
    __syncthreads();
  }

  // ---- recurrence
  for (int t = 0; t < T_; t++){
    // prefetch x_{t+1}
    int tn = (t + 1 < T_) ? (t + 1) : (T_ - 1);
    f32x4 xb[3];
    {
      const float* xp = x + ((size_t)b*T_ + tn) * N_ * F_;
      int f0 = (tid & 63)*4;
      #pragma unroll
      for (int p = 0; p < 3; p++)
        xb[p] = *(const f32x4*)(xp + (p*8 + w)*F_ + f0);
    }

    // half A: u cols 0..511 (i,f gates)
    f32x4 vA[4][2];
    {
      f32x4 acc[4][2] = {};
      gemm_half<16,512>(acc, Alds, wcat, 0, ctA, l15, g);
      ut_write(uTl, acc, ctA, l15, g);
      __syncthreads();                  // b1: u^T visible
      nodemix(vA, uTl, ctA, l15, g, gb0, gb1);
      __syncthreads();                  // b2: u^T reads done
    }
    // half B: u cols 512..1023 (g,o gates)
    f32x4 vB[4][2];
    {
      f32x4 acc[4][2] = {};
      gemm_half<16,512>(acc, Alds, wcat, 0, ctB, l15, g);
      ut_write(uTl, acc, ctB, l15, g);
      __syncthreads();                  // b3
      nodemix(vB, uTl, ctB, l15, g, gb0, gb1);
    }
    // pointwise LSTM + h write
    #pragma unroll
    for (int p = 0; p < 2; p++){
      #pragma unroll
      for (int nt = 0; nt < 2; nt++){
        float hv[4];
        #pragma unroll
        for (int r = 0; r < 4; r++){
          float ig = fsig  (vA[p  ][nt][r] + bi [p][r]);
          float fg = fsig  (vA[2+p][nt][r] + bff[p][r]);
          float gg = ftanh_(vB[p  ][nt][r] + bg [p][r]);
          float og = fsig  (vB[2+p][nt][r] + bo [p][r]);
          float cs = fg * c_state[p][nt][r] + ig * gg;
          c_state[p][nt][r] = cs;
          hv[r] = og * ftanh_(cs);
        }
        int n = l15 + 16*nt;
        if (n < 24){
          uint2 pk; pk.x = pk2bf(hv[0], hv[1]); pk.y = pk2bf(hv[2], hv[3]);
          int c0 = (8*p + w)*16 + g*4;
          *(uint2*)&Alds[n*LDA + ((256 + c0) ^ ((n&7)<<3))] = pk;
        }
      }
    }
    // write prefetched x_{t+1}
    {
      int f0 = (tid & 63)*4;
      #pragma unroll
      for (int p = 0; p < 3; p++){
        int n = p*8 + w;
        uint2 pk; pk.x = pk2bf(xb[p][0], xb[p][1]); pk.y = pk2bf(xb[p][2], xb[p][3]);
        *(uint2*)&Alds[n*LDA + (f0 ^ ((n&7)<<3))] = pk;
      }
    }
    __syncthreads();                    // b4: next step may read A
  }

  // ---- final: out = tanh(G(h Wfc^T) + bfc)
  {
    const int ctF[4] = {w, 8+w, w, 8+w};
    f32x4 acc[4][2] = {};
    gemm_half<8,256>(acc, Alds, wfc, 8, ctF, l15, g);   // A k = 256..511 (h)
    ut_write(uTl, acc, ctF, l15, g);
    __syncthreads();
    f32x4 v[4][2];
    nodemix(v, uTl, ctF, l15, g, gb0, gb1);
    #pragma unroll
    for (int p = 0; p < 2; p++){
      float bfcv[4];
      #pragma unroll
      for (int r = 0; r < 4; r++) bfcv[r] = bfcp[(8*p + w)*16 + g*4 + r];
      #pragma unroll
      for (int nt = 0; nt < 2; nt++){
        int n = l15 + 16*nt;
        if (n < 24){
          f32x4 ov;
          #pragma unroll
          for (int r = 0; r < 4; r++) ov[r] = ftanh_(v[p][nt][r] + bfcv[r]);
          int c0 = (8*p + w)*16 + g*4;
          *(f32x4*)&out[((size_t)b*24 + n)*256 + c0] = ov;
        }
      }
    }
  }
}

extern "C" void kernel_launch(void* const* d_in, const int* in_sizes, int n_in,
                              void* d_out, int out_size, void* d_ws, size_t ws_size,
                              hipStream_t stream)
{
  (void)in_sizes; (void)n_in; (void)out_size;
  if (ws_size < WS_NEED) return;   // loud failure via validation rather than OOB

  const float* x   = (const float*)d_in[0];
  const float* G   = (const float*)d_in[1];
  const float* Wih = (const float*)d_in[2];
  const float* bih = (const float*)d_in[3];
  const float* Whh = (const float*)d_in[4];
  const float* bhh = (const float*)d_in[5];
  const float* Wh1 = (const float*)d_in[6];
  const float* bh1 = (const float*)d_in[7];
  const float* Wh2 = (const float*)d_in[8];
  const float* bh2 = (const float*)d_in[9];
  const float* Wfc = (const float*)d_in[10];
  const float* bfc = (const float*)d_in[11];
  uint8_t* ws = (uint8_t*)d_ws;

  hipLaunchKernelGGL(prep_kernel, dim3(128), dim3(256), 0, stream,
                     G, Wih, bih, Whh, bhh, Wh1, bh1, Wh2, bh2, Wfc, bfc, ws);
  hipLaunchKernelGGL(encoder_kernel, dim3(64), dim3(512), 0, stream,
                     x, (const uint8_t*)ws, (float*)d_out);
}